// Round 8
// baseline (1578.609 us; speedup 1.0000x reference)
//
#include <hip/hip_runtime.h>
#include <hip/hip_bf16.h>
#include <math.h>

#define NPTS 100000
#define PAD_ROWS 100096   // 391 * 256
#define DIM 512
#define GRP 4
#define GD 128
#define K_NBR 16
#define EPS 1e-5f

using bf16x8 = __attribute__((ext_vector_type(8))) short;
using f32x4  = __attribute__((ext_vector_type(4))) float;
using short4v = __attribute__((ext_vector_type(4))) short;

__device__ inline float bf2f(short s) {
    unsigned u = ((unsigned)(unsigned short)s) << 16;
    union { unsigned u; float f; } c; c.u = u; return c.f;
}
__device__ inline short f2bf(float f) {
    union { float f; unsigned u; } c; c.f = f;
    unsigned u = c.u;
    unsigned r = (u + 0x7fffu + ((u >> 16) & 1u)) >> 16;
    return (short)r;
}

__device__ __forceinline__ void gload_lds16(short* lds, const short* g) {
    __builtin_amdgcn_global_load_lds(
        (const __attribute__((address_space(1))) unsigned int*)g,
        (__attribute__((address_space(3))) unsigned int*)lds, 16, 0, 0);
}

// bijective XCD swizzle (m204): works for nwg % 8 != 0
__device__ __forceinline__ int xcd_map(int bid, int nwg) {
    int q = nwg >> 3, r8 = nwg & 7;
    int xcd = bid & 7, idx = bid >> 3;
    int base = (xcd < r8) ? xcd * (q + 1) : r8 * (q + 1) + (xcd - r8) * q;
    return base + idx;
}

// ---------------- weight convert f32 -> bf16 ----------------
__global__ void cvt_kernel(const float* __restrict__ src, short* __restrict__ dst, int n) {
    int i = blockIdx.x * blockDim.x + threadIdx.x;
    int stride = gridDim.x * blockDim.x;
    for (; i < n; i += stride) dst[i] = f2bf(src[i]);
}

// ---------------- Mt[g][e][d] = scale * sum_o Wq[g][o][d] * Wk[g][o][e] --------------
__global__ void prep_m_kernel(const float* __restrict__ wq, const float* __restrict__ wk,
                              short* __restrict__ mt) {
    int ge = blockIdx.x;            // g*128 + e
    int g = ge >> 7, e = ge & 127;
    int d = threadIdx.x;            // 128 threads
    const float* Wq = wq + (size_t)g * GD * GD;
    const float* Wk = wk + (size_t)g * GD * GD;
    float acc = 0.0f;
    for (int o = 0; o < GD; ++o)
        acc += Wq[(size_t)o * GD + d] * Wk[(size_t)o * GD + e];
    mt[(size_t)ge * GD + d] = f2bf(acc * 0.08838834764831845f);
}

// ---------------- Wov[o][g*128+i0] = sum_d Wo[o][g*128+d] * Wv[g][d][i0] -------------
__global__ void prep_wov_kernel(const float* __restrict__ wo, const float* __restrict__ wv,
                                short* __restrict__ wov) {
    int o = blockIdx.x;             // 512 blocks
    int i = threadIdx.x;            // 512 threads
    int g = i >> 7, i0 = i & 127;
    float acc = 0.0f;
    for (int d = 0; d < GD; ++d)
        acc += wo[(size_t)o * DIM + g * GD + d] * wv[((size_t)g * GD + d) * GD + i0];
    wov[(size_t)o * DIM + i] = f2bf(acc);
}

// ---------------- LayerNorm (f32 in -> bf16 out) ----------------
__global__ void ln_kernel(const float* __restrict__ in, const float* __restrict__ g,
                          const float* __restrict__ b, short* __restrict__ out) {
    int row = blockIdx.x;
    int tid = threadIdx.x; // 128 threads, 4 elems each
    if (row >= NPTS) {
        short4v z; z[0] = 0; z[1] = 0; z[2] = 0; z[3] = 0;
        *(short4v*)(out + (size_t)row * DIM + tid * 4) = z;
        return;
    }
    const float4 x = *(const float4*)(in + (size_t)row * DIM + tid * 4);
    float s  = x.x + x.y + x.z + x.w;
    float sq = x.x * x.x + x.y * x.y + x.z * x.z + x.w * x.w;
    for (int m = 1; m < 64; m <<= 1) {
        s  += __shfl_xor(s, m);
        sq += __shfl_xor(sq, m);
    }
    __shared__ float ss[2], ssq[2];
    int wv = tid >> 6;
    if ((tid & 63) == 0) { ss[wv] = s; ssq[wv] = sq; }
    __syncthreads();
    s = ss[0] + ss[1]; sq = ssq[0] + ssq[1];
    float mu = s * (1.0f / DIM);
    float var = sq * (1.0f / DIM) - mu * mu;
    float rstd = rsqrtf(var + EPS);
    const float4 gg = *(const float4*)(g + tid * 4);
    const float4 bb = *(const float4*)(b + tid * 4);
    short4v o;
    o[0] = f2bf((x.x - mu) * rstd * gg.x + bb.x);
    o[1] = f2bf((x.y - mu) * rstd * gg.y + bb.y);
    o[2] = f2bf((x.z - mu) * rstd * gg.z + bb.z);
    o[3] = f2bf((x.w - mu) * rstd * gg.w + bb.w);
    *(short4v*)(out + (size_t)row * DIM + tid * 4) = o;
}

// ================= 256x256 GEMM core, BK=64, 8 waves (2Mx4N), 2-phase dbuf ===========
#define TSZ (256 * 64)

__device__ __forceinline__ void stage256(short* As, short* Bs,
        const short* aS, int as_, const short* bS, int bs_, int tid) {
    int ldRow = tid >> 3;            // 0..63
    int ldCol = (tid & 7) * 8;       // element col within BK=64
    #pragma unroll
    for (int i = 0; i < 4; ++i) {
        gload_lds16(As + (ldRow + i * 64) * 64 + ldCol, aS + (size_t)(ldRow + i * 64) * as_ + ldCol);
        gload_lds16(Bs + (ldRow + i * 64) * 64 + ldCol, bS + (size_t)(ldRow + i * 64) * bs_ + ldCol);
    }
}

__device__ __forceinline__ void compute256(const short* As, const short* Bs,
        int wr, int wc, int r, int ks, f32x4 (&acc)[8][4]) {
    #pragma unroll
    for (int ks2 = 0; ks2 < 2; ++ks2) {
        bf16x8 a[8];
        #pragma unroll
        for (int m = 0; m < 8; ++m)
            a[m] = *(const bf16x8*)(As + (wr * 128 + m * 16 + r) * 64 + ks2 * 32 + ks * 8);
        #pragma unroll
        for (int n = 0; n < 4; ++n) {
            bf16x8 b = *(const bf16x8*)(Bs + (wc * 64 + n * 16 + r) * 64 + ks2 * 32 + ks * 8);
            #pragma unroll
            for (int m = 0; m < 8; ++m)
                acc[m][n] = __builtin_amdgcn_mfma_f32_16x16x32_bf16(a[m], b, acc[m][n], 0, 0, 0);
        }
    }
}

// NT even. Per K-tile: STAGE(next) -> COMPUTE(cur) -> barrier.
template<int NT>
__device__ __forceinline__ void gemm256(
        const short* __restrict__ aBase, int as_,
        const short* __restrict__ bBase, int bs_,
        short* As, short* Bs, f32x4 (&acc)[8][4]) {
    int tid = threadIdx.x;
    int lane = tid & 63, wave = tid >> 6;
    int wr = wave >> 2, wc = wave & 3;
    int r = lane & 15, ks = lane >> 4;
    stage256(As, Bs, aBase, as_, bBase, bs_, tid);
    __syncthreads();
    for (int kt = 0; kt < NT; kt += 2) {
        if (kt + 1 < NT)
            stage256(As + TSZ, Bs + TSZ, aBase + (kt + 1) * 64, as_, bBase + (kt + 1) * 64, bs_, tid);
        compute256(As, Bs, wr, wc, r, ks, acc);
        __syncthreads();
        if (kt + 2 < NT)
            stage256(As, Bs, aBase + (kt + 2) * 64, as_, bBase + (kt + 2) * 64, bs_, tid);
        compute256(As + TSZ, Bs + TSZ, wr, wc, r, ks, acc);
        __syncthreads();
    }
}

#define GEMM256_PRE \
    __shared__ short As[2 * TSZ], Bs[2 * TSZ]; \
    int tid = threadIdx.x; \
    int lane = tid & 63, wave = tid >> 6; \
    int wr = wave >> 2, wc = wave & 3; \
    int r = lane & 15, ks = lane >> 4; \
    f32x4 acc[8][4]; \
    _Pragma("unroll") \
    for (int m = 0; m < 8; ++m) \
        _Pragma("unroll") \
        for (int n = 0; n < 4; ++n) \
            _Pragma("unroll") \
            for (int e = 0; e < 4; ++e) acc[m][n][e] = 0.0f;

// ---------------- old 128x128 core (kept for qproj, K=128) ---------------------------
__device__ __forceinline__ void stage_tile(short* As, short* Bs,
        const short* aS, int as_, const short* bS, int bs_, int tid) {
    int ldRow = tid >> 2;
    int ldCol = (tid & 3) * 8;
    gload_lds16(As + (ldRow)      * 32 + ldCol, aS + (size_t)(ldRow)      * as_ + ldCol);
    gload_lds16(As + (ldRow + 64) * 32 + ldCol, aS + (size_t)(ldRow + 64) * as_ + ldCol);
    gload_lds16(Bs + (ldRow)      * 32 + ldCol, bS + (size_t)(ldRow)      * bs_ + ldCol);
    gload_lds16(Bs + (ldRow + 64) * 32 + ldCol, bS + (size_t)(ldRow + 64) * bs_ + ldCol);
}

__device__ __forceinline__ void compute_tile(const short* As, const short* Bs,
        int wr, int wc, int r, int ks, f32x4 (&acc)[4][4]) {
    bf16x8 a[4];
    #pragma unroll
    for (int m = 0; m < 4; ++m)
        a[m] = *(const bf16x8*)(As + (wr * 64 + m * 16 + r) * 32 + ks * 8);
    #pragma unroll
    for (int n = 0; n < 4; ++n) {
        bf16x8 b = *(const bf16x8*)(Bs + (wc * 64 + n * 16 + r) * 32 + ks * 8);
        #pragma unroll
        for (int m = 0; m < 4; ++m)
            acc[m][n] = __builtin_amdgcn_mfma_f32_16x16x32_bf16(a[m], b, acc[m][n], 0, 0, 0);
    }
}

template<int NK>
__device__ __forceinline__ void gemm_tile(
        const short* __restrict__ aBase, int as_,
        const short* __restrict__ bBase, int bs_,
        short* As0, short* Bs0, short* As1, short* Bs1, f32x4 (&acc)[4][4]) {
    int tid = threadIdx.x;
    int lane = tid & 63, wave = tid >> 6;
    int wr = wave >> 1, wc = wave & 1;
    int r = lane & 15, ks = lane >> 4;
    stage_tile(As0, Bs0, aBase, as_, bBase, bs_, tid);
    __syncthreads();
    #pragma unroll
    for (int kt = 0; kt < NK; kt += 2) {
        if (kt + 1 < NK)
            stage_tile(As1, Bs1, aBase + (kt + 1) * 32, as_, bBase + (kt + 1) * 32, bs_, tid);
        compute_tile(As0, Bs0, wr, wc, r, ks, acc);
        __syncthreads();
        if (kt + 2 < NK)
            stage_tile(As0, Bs0, aBase + (kt + 2) * 32, as_, bBase + (kt + 2) * 32, bs_, tid);
        compute_tile(As1, Bs1, wr, wc, r, ks, acc);
        __syncthreads();
    }
}

// ---------------- q' projection: q'[n][g*128+e] = sum_d x[n][g*128+d] * Mt[g][e][d] ---
__global__ __launch_bounds__(256) void qproj_kernel(
        const short* __restrict__ x, const short* __restrict__ mt,
        short* __restrict__ qp) {
    __shared__ short As0[128 * 32], Bs0[128 * 32], As1[128 * 32], Bs1[128 * 32];
    int nwg = gridDim.x;
    int bid = blockIdx.x;
    int tile = xcd_map(bid, nwg);
    int rb = tile >> 2, g = tile & 3;
    int rowbase = rb * 128;
    int tid = threadIdx.x;
    int lane = tid & 63, wave = tid >> 6;
    int wr = wave >> 1, wc = wave & 1;
    int r = lane & 15, ks = lane >> 4;
    f32x4 acc[4][4];
    #pragma unroll
    for (int m = 0; m < 4; ++m)
        #pragma unroll
        for (int n = 0; n < 4; ++n)
            #pragma unroll
            for (int e = 0; e < 4; ++e) acc[m][n][e] = 0.0f;
    gemm_tile<4>(x + (size_t)rowbase * DIM + g * GD, DIM,
                 mt + (size_t)g * GD * GD, GD, As0, Bs0, As1, Bs1, acc);
    #pragma unroll
    for (int m = 0; m < 4; ++m)
        #pragma unroll
        for (int n = 0; n < 4; ++n)
            #pragma unroll
            for (int rr = 0; rr < 4; ++rr) {
                int orow = rowbase + wr * 64 + m * 16 + ks * 4 + rr;
                int lcol = wc * 64 + n * 16 + r;
                qp[(size_t)orow * DIM + g * GD + lcol] = f2bf(acc[m][n][rr]);
            }
}

// ---------------- attention: gathers x only; t[n][g] = sum_j softmax_j * x_j[g-slice] -
__global__ __launch_bounds__(256) void attn_kernel(
        const short* __restrict__ qp, const short* __restrict__ x,
        const int* __restrict__ nbrs, short* __restrict__ t_out) {
    int b = blockIdx.x;
    int xcd = b & 7;
    int g = xcd >> 1;
    int quad = (b >> 3) * 2 + (xcd & 1);   // 0..24999
    int tid = threadIdx.x;
    int wv = tid >> 6, lane = tid & 63;
    int n = quad * 4 + wv;                 // 0..99999
    int s = lane >> 4, t = lane & 15;
    int4 nbj = *(const int4*)(nbrs + (size_t)n * K_NBR + s * 4);
    int nbarr[4] = {nbj.x, nbj.y, nbj.z, nbj.w};
    size_t goff = (size_t)g * GD + t * 8;
    size_t qbase = (size_t)n * DIM + goff;
    bf16x8 qf = *(const bf16x8*)(qp + qbase);
    float qv[8];
    #pragma unroll
    for (int e = 0; e < 8; ++e) qv[e] = bf2f(qf[e]);
    bf16x8 xf[4];
    #pragma unroll
    for (int p = 0; p < 4; ++p)
        xf[p] = *(const bf16x8*)(x + (size_t)nbarr[p] * DIM + goff);
    float sc[4];
    #pragma unroll
    for (int p = 0; p < 4; ++p) {
        float dd = 0.0f;
        #pragma unroll
        for (int e = 0; e < 8; ++e) dd += qv[e] * bf2f(xf[p][e]);
        dd += __shfl_xor(dd, 1);
        dd += __shfl_xor(dd, 2);
        dd += __shfl_xor(dd, 4);
        dd += __shfl_xor(dd, 8);
        sc[p] = dd;
    }
    float mx = fmaxf(fmaxf(sc[0], sc[1]), fmaxf(sc[2], sc[3]));
    mx = fmaxf(mx, __shfl_xor(mx, 16));
    mx = fmaxf(mx, __shfl_xor(mx, 32));
    float ew[4]; float ssum = 0.0f;
    #pragma unroll
    for (int p = 0; p < 4; ++p) { ew[p] = __expf(sc[p] - mx); ssum += ew[p]; }
    ssum += __shfl_xor(ssum, 16);
    ssum += __shfl_xor(ssum, 32);
    float acc[8];
    #pragma unroll
    for (int d0 = 0; d0 < 8; ++d0) acc[d0] = 0.0f;
    #pragma unroll
    for (int p = 0; p < 4; ++p) {
        #pragma unroll
        for (int d0 = 0; d0 < 8; ++d0) acc[d0] += ew[p] * bf2f(xf[p][d0]);
    }
    #pragma unroll
    for (int d0 = 0; d0 < 8; ++d0) {
        acc[d0] += __shfl_xor(acc[d0], 16);
        acc[d0] += __shfl_xor(acc[d0], 32);
    }
    if (s == 0) {
        float inv = 1.0f / ssum;
        bf16x8 o;
        #pragma unroll
        for (int d0 = 0; d0 < 8; ++d0) o[d0] = f2bf(acc[d0] * inv);
        *(bf16x8*)(t_out + qbase) = o;
    }
}

// ---------------- out = t @ Wov.T + bo + features (residual) -> f32 d_out -------------
__global__ __launch_bounds__(512, 2) void outproj_kernel(
        const short* __restrict__ tbuf, const short* __restrict__ wov,
        const float* __restrict__ bo, const float* __restrict__ features,
        float* __restrict__ out) {
    GEMM256_PRE;
    int tile = xcd_map(blockIdx.x, gridDim.x);   // 391*2 blocks
    int rt = tile >> 1, ct = tile & 1;
    int rowbase = rt * 256, colbase = ct * 256;
    gemm256<8>(tbuf + (size_t)rowbase * DIM, DIM,
               wov + (size_t)colbase * DIM, DIM, As, Bs, acc);
    #pragma unroll
    for (int m = 0; m < 8; ++m)
        #pragma unroll
        for (int n = 0; n < 4; ++n)
            #pragma unroll
            for (int rr = 0; rr < 4; ++rr) {
                int orow = rowbase + wr * 128 + m * 16 + ks * 4 + rr;
                int ocol = colbase + wc * 64 + n * 16 + r;
                if (orow < NPTS) {
                    out[(size_t)orow * DIM + ocol] =
                        acc[m][n][rr] + bo[ocol] + features[(size_t)orow * DIM + ocol];
                }
            }
}

// ---------------- FFN1: h = gelu(y @ W1.T + b1), bf16 out, N=1024 --------------------
__global__ __launch_bounds__(512, 2) void ffn1_kernel(
        const short* __restrict__ y, const short* __restrict__ w1,
        const float* __restrict__ b1, short* __restrict__ h) {
    GEMM256_PRE;
    int tile = xcd_map(blockIdx.x, gridDim.x);   // 391*4 blocks
    int rt = tile >> 2, ct = tile & 3;
    int rowbase = rt * 256, colbase = ct * 256;
    gemm256<8>(y + (size_t)rowbase * DIM, DIM,
               w1 + (size_t)colbase * DIM, DIM, As, Bs, acc);
    #pragma unroll
    for (int m = 0; m < 8; ++m)
        #pragma unroll
        for (int n = 0; n < 4; ++n)
            #pragma unroll
            for (int rr = 0; rr < 4; ++rr) {
                int orow = rowbase + wr * 128 + m * 16 + ks * 4 + rr;
                int ocol = colbase + wc * 64 + n * 16 + r;
                float xv = acc[m][n][rr] + b1[ocol];
                // exact-GELU via clamped tanh form (max abs err ~3e-3)
                float xc = fminf(fmaxf(xv, -9.0f), 9.0f);
                float u = xc * (0.7978845608028654f + 0.0356774081f * xc * xc);
                float e2 = __expf(2.0f * u);
                float th = (e2 - 1.0f) / (e2 + 1.0f);
                float gl = 0.5f * xv * (1.0f + th);
                h[(size_t)orow * (2 * DIM) + ocol] = f2bf(gl);
            }
}

// ---------------- FFN2: d_out = h @ W2.T + b2 + d_out(res2), K=1024 ------------------
__global__ __launch_bounds__(512, 2) void ffn2_kernel(
        const short* __restrict__ h, const short* __restrict__ w2,
        const float* __restrict__ b2, float* __restrict__ out) {
    GEMM256_PRE;
    int tile = xcd_map(blockIdx.x, gridDim.x);   // 391*2 blocks
    int rt = tile >> 1, ct = tile & 1;
    int rowbase = rt * 256, colbase = ct * 256;
    gemm256<16>(h + (size_t)rowbase * (2 * DIM), 2 * DIM,
                w2 + (size_t)colbase * (2 * DIM), 2 * DIM, As, Bs, acc);
    #pragma unroll
    for (int m = 0; m < 8; ++m)
        #pragma unroll
        for (int n = 0; n < 4; ++n)
            #pragma unroll
            for (int rr = 0; rr < 4; ++rr) {
                int orow = rowbase + wr * 128 + m * 16 + ks * 4 + rr;
                int ocol = colbase + wc * 64 + n * 16 + r;
                if (orow < NPTS) {
                    size_t idx = (size_t)orow * DIM + ocol;
                    out[idx] = acc[m][n][rr] + b2[ocol] + out[idx];
                }
            }
}

extern "C" void kernel_launch(void* const* d_in, const int* in_sizes, int n_in,
                              void* d_out, int out_size, void* d_ws, size_t ws_size,
                              hipStream_t stream) {
    const float* features = (const float*)d_in[0];
    const int*   neighbors = (const int*)d_in[2];
    const float* Wq = (const float*)d_in[3];
    const float* Wk = (const float*)d_in[4];
    const float* Wv = (const float*)d_in[5];
    const float* Wo = (const float*)d_in[6];
    const float* bo = (const float*)d_in[7];
    const float* ln1_g = (const float*)d_in[8];
    const float* ln1_b = (const float*)d_in[9];
    const float* ln2_g = (const float*)d_in[10];
    const float* ln2_b = (const float*)d_in[11];
    const float* W1 = (const float*)d_in[12];
    const float* b1 = (const float*)d_in[13];
    const float* W2 = (const float*)d_in[14];
    const float* b2 = (const float*)d_in[15];
    float* out = (float*)d_out;

    size_t slotElems = (size_t)PAD_ROWS * DIM;
    short* s0 = (short*)d_ws;            // x (ln1) -> y (ln2)
    short* s1 = s0 + slotElems;          // q' -> h (low half; s1+s2 contiguous = h[PAD][1024])
    short* s2 = s1 + slotElems;          // t  -> h (high half)
    short* mt_b  = s2 + slotElems;       // 4*128*128
    short* wov_b = mt_b + GRP * GD * GD; // 512*512
    short* w1_b  = wov_b + DIM * DIM;    // 1024*512
    short* w2_b  = w1_b + 2 * DIM * DIM; // 512*1024

    cvt_kernel<<<256, 256, 0, stream>>>(W1, w1_b, 2 * DIM * DIM);
    cvt_kernel<<<256, 256, 0, stream>>>(W2, w2_b, 2 * DIM * DIM);
    prep_m_kernel<<<GRP * GD, GD, 0, stream>>>(Wq, Wk, mt_b);
    prep_wov_kernel<<<DIM, DIM, 0, stream>>>(Wo, Wv, wov_b);

    // LN1: features -> x (bf16), zero-padded rows
    ln_kernel<<<PAD_ROWS, 128, 0, stream>>>(features, ln1_g, ln1_b, s0);

    // q' = Mt x (single grouped GEMM pass, 128^2 core)
    qproj_kernel<<<(PAD_ROWS / 128) * 4, 256, 0, stream>>>(s0, mt_b, s1);

    // attention: gather x only -> t in s2
    attn_kernel<<<NPTS, 256, 0, stream>>>(s1, s0, neighbors, s2);

    // out = t @ Wov.T + bo + features  (f32, in d_out)  [256^2 core]
    outproj_kernel<<<(PAD_ROWS / 256) * 2, 512, 0, stream>>>(s2, wov_b, bo, features, out);

    // LN2: d_out -> y (bf16) in s0
    ln_kernel<<<PAD_ROWS, 128, 0, stream>>>(out, ln2_g, ln2_b, s0);

    // FFN1: h = gelu(y @ W1.T + b1) -> s1..s2 region (PAD x 1024 bf16)  [256^2 core]
    ffn1_kernel<<<(PAD_ROWS / 256) * 4, 512, 0, stream>>>(s0, w1_b, b1, s1);

    // FFN2: d_out = h @ W2.T + b2 + d_out  [256^2 core]
    ffn2_kernel<<<(PAD_ROWS / 256) * 2, 512, 0, stream>>>(s1, w2_b, b2, out);
}

// Round 9
// 1326.537 us; speedup vs baseline: 1.1900x; 1.1900x over previous
//
#include <hip/hip_runtime.h>
#include <hip/hip_bf16.h>
#include <math.h>

#define NPTS 100000
#define PAD_ROWS 100096   // 391 * 256
#define DIM 512
#define GRP 4
#define GD 128
#define K_NBR 16
#define EPS 1e-5f

using bf16x8 = __attribute__((ext_vector_type(8))) short;
using f32x4  = __attribute__((ext_vector_type(4))) float;
using short4v = __attribute__((ext_vector_type(4))) short;

__device__ inline float bf2f(short s) {
    unsigned u = ((unsigned)(unsigned short)s) << 16;
    union { unsigned u; float f; } c; c.u = u; return c.f;
}
__device__ inline short f2bf(float f) {
    union { float f; unsigned u; } c; c.f = f;
    unsigned u = c.u;
    unsigned r = (u + 0x7fffu + ((u >> 16) & 1u)) >> 16;
    return (short)r;
}

__device__ __forceinline__ void gload_lds16(short* lds, const short* g) {
    __builtin_amdgcn_global_load_lds(
        (const __attribute__((address_space(1))) unsigned int*)g,
        (__attribute__((address_space(3))) unsigned int*)lds, 16, 0, 0);
}

// bijective XCD swizzle (m204): works for nwg % 8 != 0
__device__ __forceinline__ int xcd_map(int bid, int nwg) {
    int q = nwg >> 3, r8 = nwg & 7;
    int xcd = bid & 7, idx = bid >> 3;
    int base = (xcd < r8) ? xcd * (q + 1) : r8 * (q + 1) + (xcd - r8) * q;
    return base + idx;
}

// ---------------- weight convert f32 -> bf16 ----------------
__global__ void cvt_kernel(const float* __restrict__ src, short* __restrict__ dst, int n) {
    int i = blockIdx.x * blockDim.x + threadIdx.x;
    int stride = gridDim.x * blockDim.x;
    for (; i < n; i += stride) dst[i] = f2bf(src[i]);
}

// ---------------- Mt[g][e][d] = scale * sum_o Wq[g][o][d] * Wk[g][o][e] --------------
__global__ void prep_m_kernel(const float* __restrict__ wq, const float* __restrict__ wk,
                              short* __restrict__ mt) {
    int ge = blockIdx.x;            // g*128 + e
    int g = ge >> 7, e = ge & 127;
    int d = threadIdx.x;            // 128 threads
    const float* Wq = wq + (size_t)g * GD * GD;
    const float* Wk = wk + (size_t)g * GD * GD;
    float acc = 0.0f;
    for (int o = 0; o < GD; ++o)
        acc += Wq[(size_t)o * GD + d] * Wk[(size_t)o * GD + e];
    mt[(size_t)ge * GD + d] = f2bf(acc * 0.08838834764831845f);
}

// ---------------- Wov[o][g*128+i0] = sum_d Wo[o][g*128+d] * Wv[g][d][i0] -------------
__global__ void prep_wov_kernel(const float* __restrict__ wo, const float* __restrict__ wv,
                                short* __restrict__ wov) {
    int o = blockIdx.x;             // 512 blocks
    int i = threadIdx.x;            // 512 threads
    int g = i >> 7, i0 = i & 127;
    float acc = 0.0f;
    for (int d = 0; d < GD; ++d)
        acc += wo[(size_t)o * DIM + g * GD + d] * wv[((size_t)g * GD + d) * GD + i0];
    wov[(size_t)o * DIM + i] = f2bf(acc);
}

// ---------------- LayerNorm (f32 in -> bf16 out) ----------------
__global__ void ln_kernel(const float* __restrict__ in, const float* __restrict__ g,
                          const float* __restrict__ b, short* __restrict__ out) {
    int row = blockIdx.x;
    int tid = threadIdx.x; // 128 threads, 4 elems each
    if (row >= NPTS) {
        short4v z; z[0] = 0; z[1] = 0; z[2] = 0; z[3] = 0;
        *(short4v*)(out + (size_t)row * DIM + tid * 4) = z;
        return;
    }
    const float4 x = *(const float4*)(in + (size_t)row * DIM + tid * 4);
    float s  = x.x + x.y + x.z + x.w;
    float sq = x.x * x.x + x.y * x.y + x.z * x.z + x.w * x.w;
    for (int m = 1; m < 64; m <<= 1) {
        s  += __shfl_xor(s, m);
        sq += __shfl_xor(sq, m);
    }
    __shared__ float ss[2], ssq[2];
    int wv = tid >> 6;
    if ((tid & 63) == 0) { ss[wv] = s; ssq[wv] = sq; }
    __syncthreads();
    s = ss[0] + ss[1]; sq = ssq[0] + ssq[1];
    float mu = s * (1.0f / DIM);
    float var = sq * (1.0f / DIM) - mu * mu;
    float rstd = rsqrtf(var + EPS);
    const float4 gg = *(const float4*)(g + tid * 4);
    const float4 bb = *(const float4*)(b + tid * 4);
    short4v o;
    o[0] = f2bf((x.x - mu) * rstd * gg.x + bb.x);
    o[1] = f2bf((x.y - mu) * rstd * gg.y + bb.y);
    o[2] = f2bf((x.z - mu) * rstd * gg.z + bb.z);
    o[3] = f2bf((x.w - mu) * rstd * gg.w + bb.w);
    *(short4v*)(out + (size_t)row * DIM + tid * 4) = o;
}

// ================= 256x256 GEMM core, BK=64, 8 waves (2Mx4N), 2-phase dbuf ===========
// LDS rows are 128B -> linear layout is a 16-way bank conflict on ds_read_b128.
// Fix (T2 + rule #21): LDS dest stays LINEAR (tid*16, required by global_load_lds);
// the GLOBAL source is chunk-permuted (c ^ (row&7)), and reads apply the same XOR.
#define TSZ (256 * 64)

__device__ __forceinline__ void stage256(short* As, short* Bs,
        const short* aS, int as_, const short* bS, int bs_, int tid) {
    int row0 = tid >> 3;             // 0..63
    int c = tid & 7;                 // 16B chunk within 64-elem row
    #pragma unroll
    for (int i = 0; i < 4; ++i) {
        int row = row0 + i * 64;
        int sc = (c ^ (row & 7)) * 8;         // pre-swizzled global source chunk
        gload_lds16(As + row * 64 + c * 8, aS + (size_t)row * as_ + sc);
        gload_lds16(Bs + row * 64 + c * 8, bS + (size_t)row * bs_ + sc);
    }
}

__device__ __forceinline__ void compute256(const short* As, const short* Bs,
        int wr, int wc, int r, int ks, f32x4 (&acc)[8][4]) {
    #pragma unroll
    for (int ks2 = 0; ks2 < 2; ++ks2) {
        int kc = ks2 * 4 + ks;
        bf16x8 a[8];
        #pragma unroll
        for (int m = 0; m < 8; ++m) {
            int row = wr * 128 + m * 16 + r;
            a[m] = *(const bf16x8*)(As + row * 64 + ((kc ^ (row & 7)) * 8));
        }
        #pragma unroll
        for (int n = 0; n < 4; ++n) {
            int brow = wc * 64 + n * 16 + r;
            bf16x8 b = *(const bf16x8*)(Bs + brow * 64 + ((kc ^ (brow & 7)) * 8));
            #pragma unroll
            for (int m = 0; m < 8; ++m)
                acc[m][n] = __builtin_amdgcn_mfma_f32_16x16x32_bf16(a[m], b, acc[m][n], 0, 0, 0);
        }
    }
}

// NT even. Per K-tile: STAGE(next) -> COMPUTE(cur) -> barrier.
template<int NT>
__device__ __forceinline__ void gemm256(
        const short* __restrict__ aBase, int as_,
        const short* __restrict__ bBase, int bs_,
        short* As, short* Bs, f32x4 (&acc)[8][4]) {
    int tid = threadIdx.x;
    int lane = tid & 63, wave = tid >> 6;
    int wr = wave >> 2, wc = wave & 3;
    int r = lane & 15, ks = lane >> 4;
    stage256(As, Bs, aBase, as_, bBase, bs_, tid);
    __syncthreads();
    for (int kt = 0; kt < NT; kt += 2) {
        if (kt + 1 < NT)
            stage256(As + TSZ, Bs + TSZ, aBase + (kt + 1) * 64, as_, bBase + (kt + 1) * 64, bs_, tid);
        compute256(As, Bs, wr, wc, r, ks, acc);
        __syncthreads();
        if (kt + 2 < NT)
            stage256(As, Bs, aBase + (kt + 2) * 64, as_, bBase + (kt + 2) * 64, bs_, tid);
        compute256(As + TSZ, Bs + TSZ, wr, wc, r, ks, acc);
        __syncthreads();
    }
}

#define GEMM256_PRE \
    __shared__ short As[2 * TSZ], Bs[2 * TSZ]; \
    int tid = threadIdx.x; \
    int lane = tid & 63, wave = tid >> 6; \
    int wr = wave >> 2, wc = wave & 3; \
    int r = lane & 15, ks = lane >> 4; \
    f32x4 acc[8][4]; \
    _Pragma("unroll") \
    for (int m = 0; m < 8; ++m) \
        _Pragma("unroll") \
        for (int n = 0; n < 4; ++n) \
            _Pragma("unroll") \
            for (int e = 0; e < 4; ++e) acc[m][n][e] = 0.0f;

// ---------------- old 128x128 core (kept for qproj, K=128) ---------------------------
__device__ __forceinline__ void stage_tile(short* As, short* Bs,
        const short* aS, int as_, const short* bS, int bs_, int tid) {
    int ldRow = tid >> 2;
    int ldCol = (tid & 3) * 8;
    gload_lds16(As + (ldRow)      * 32 + ldCol, aS + (size_t)(ldRow)      * as_ + ldCol);
    gload_lds16(As + (ldRow + 64) * 32 + ldCol, aS + (size_t)(ldRow + 64) * as_ + ldCol);
    gload_lds16(Bs + (ldRow)      * 32 + ldCol, bS + (size_t)(ldRow)      * bs_ + ldCol);
    gload_lds16(Bs + (ldRow + 64) * 32 + ldCol, bS + (size_t)(ldRow + 64) * bs_ + ldCol);
}

__device__ __forceinline__ void compute_tile(const short* As, const short* Bs,
        int wr, int wc, int r, int ks, f32x4 (&acc)[4][4]) {
    bf16x8 a[4];
    #pragma unroll
    for (int m = 0; m < 4; ++m)
        a[m] = *(const bf16x8*)(As + (wr * 64 + m * 16 + r) * 32 + ks * 8);
    #pragma unroll
    for (int n = 0; n < 4; ++n) {
        bf16x8 b = *(const bf16x8*)(Bs + (wc * 64 + n * 16 + r) * 32 + ks * 8);
        #pragma unroll
        for (int m = 0; m < 4; ++m)
            acc[m][n] = __builtin_amdgcn_mfma_f32_16x16x32_bf16(a[m], b, acc[m][n], 0, 0, 0);
    }
}

template<int NK>
__device__ __forceinline__ void gemm_tile(
        const short* __restrict__ aBase, int as_,
        const short* __restrict__ bBase, int bs_,
        short* As0, short* Bs0, short* As1, short* Bs1, f32x4 (&acc)[4][4]) {
    int tid = threadIdx.x;
    int lane = tid & 63, wave = tid >> 6;
    int wr = wave >> 1, wc = wave & 1;
    int r = lane & 15, ks = lane >> 4;
    stage_tile(As0, Bs0, aBase, as_, bBase, bs_, tid);
    __syncthreads();
    #pragma unroll
    for (int kt = 0; kt < NK; kt += 2) {
        if (kt + 1 < NK)
            stage_tile(As1, Bs1, aBase + (kt + 1) * 32, as_, bBase + (kt + 1) * 32, bs_, tid);
        compute_tile(As0, Bs0, wr, wc, r, ks, acc);
        __syncthreads();
        if (kt + 2 < NK)
            stage_tile(As0, Bs0, aBase + (kt + 2) * 32, as_, bBase + (kt + 2) * 32, bs_, tid);
        compute_tile(As1, Bs1, wr, wc, r, ks, acc);
        __syncthreads();
    }
}

// ---------------- q' projection: q'[n][g*128+e] = sum_d x[n][g*128+d] * Mt[g][e][d] ---
__global__ __launch_bounds__(256) void qproj_kernel(
        const short* __restrict__ x, const short* __restrict__ mt,
        short* __restrict__ qp) {
    __shared__ short As0[128 * 32], Bs0[128 * 32], As1[128 * 32], Bs1[128 * 32];
    int nwg = gridDim.x;
    int bid = blockIdx.x;
    int tile = xcd_map(bid, nwg);
    int rb = tile >> 2, g = tile & 3;
    int rowbase = rb * 128;
    int tid = threadIdx.x;
    int lane = tid & 63, wave = tid >> 6;
    int wr = wave >> 1, wc = wave & 1;
    int r = lane & 15, ks = lane >> 4;
    f32x4 acc[4][4];
    #pragma unroll
    for (int m = 0; m < 4; ++m)
        #pragma unroll
        for (int n = 0; n < 4; ++n)
            #pragma unroll
            for (int e = 0; e < 4; ++e) acc[m][n][e] = 0.0f;
    gemm_tile<4>(x + (size_t)rowbase * DIM + g * GD, DIM,
                 mt + (size_t)g * GD * GD, GD, As0, Bs0, As1, Bs1, acc);
    #pragma unroll
    for (int m = 0; m < 4; ++m)
        #pragma unroll
        for (int n = 0; n < 4; ++n)
            #pragma unroll
            for (int rr = 0; rr < 4; ++rr) {
                int orow = rowbase + wr * 64 + m * 16 + ks * 4 + rr;
                int lcol = wc * 64 + n * 16 + r;
                qp[(size_t)orow * DIM + g * GD + lcol] = f2bf(acc[m][n][rr]);
            }
}

// ---------------- attention: gathers x only; t[n][g] = sum_j softmax_j * x_j[g-slice] -
__global__ __launch_bounds__(256) void attn_kernel(
        const short* __restrict__ qp, const short* __restrict__ x,
        const int* __restrict__ nbrs, short* __restrict__ t_out) {
    int b = blockIdx.x;
    int xcd = b & 7;
    int g = xcd >> 1;
    int quad = (b >> 3) * 2 + (xcd & 1);   // 0..24999
    int tid = threadIdx.x;
    int wv = tid >> 6, lane = tid & 63;
    int n = quad * 4 + wv;                 // 0..99999
    int s = lane >> 4, t = lane & 15;
    int4 nbj = *(const int4*)(nbrs + (size_t)n * K_NBR + s * 4);
    int nbarr[4] = {nbj.x, nbj.y, nbj.z, nbj.w};
    size_t goff = (size_t)g * GD + t * 8;
    size_t qbase = (size_t)n * DIM + goff;
    bf16x8 qf = *(const bf16x8*)(qp + qbase);
    float qv[8];
    #pragma unroll
    for (int e = 0; e < 8; ++e) qv[e] = bf2f(qf[e]);
    bf16x8 xf[4];
    #pragma unroll
    for (int p = 0; p < 4; ++p)
        xf[p] = *(const bf16x8*)(x + (size_t)nbarr[p] * DIM + goff);
    float sc[4];
    #pragma unroll
    for (int p = 0; p < 4; ++p) {
        float dd = 0.0f;
        #pragma unroll
        for (int e = 0; e < 8; ++e) dd += qv[e] * bf2f(xf[p][e]);
        dd += __shfl_xor(dd, 1);
        dd += __shfl_xor(dd, 2);
        dd += __shfl_xor(dd, 4);
        dd += __shfl_xor(dd, 8);
        sc[p] = dd;
    }
    float mx = fmaxf(fmaxf(sc[0], sc[1]), fmaxf(sc[2], sc[3]));
    mx = fmaxf(mx, __shfl_xor(mx, 16));
    mx = fmaxf(mx, __shfl_xor(mx, 32));
    float ew[4]; float ssum = 0.0f;
    #pragma unroll
    for (int p = 0; p < 4; ++p) { ew[p] = __expf(sc[p] - mx); ssum += ew[p]; }
    ssum += __shfl_xor(ssum, 16);
    ssum += __shfl_xor(ssum, 32);
    float acc[8];
    #pragma unroll
    for (int d0 = 0; d0 < 8; ++d0) acc[d0] = 0.0f;
    #pragma unroll
    for (int p = 0; p < 4; ++p) {
        #pragma unroll
        for (int d0 = 0; d0 < 8; ++d0) acc[d0] += ew[p] * bf2f(xf[p][d0]);
    }
    #pragma unroll
    for (int d0 = 0; d0 < 8; ++d0) {
        acc[d0] += __shfl_xor(acc[d0], 16);
        acc[d0] += __shfl_xor(acc[d0], 32);
    }
    if (s == 0) {
        float inv = 1.0f / ssum;
        bf16x8 o;
        #pragma unroll
        for (int d0 = 0; d0 < 8; ++d0) o[d0] = f2bf(acc[d0] * inv);
        *(bf16x8*)(t_out + qbase) = o;
    }
}

// ---------------- out = t @ Wov.T + bo + features (residual) -> f32 d_out -------------
__global__ __launch_bounds__(512) void outproj_kernel(
        const short* __restrict__ tbuf, const short* __restrict__ wov,
        const float* __restrict__ bo, const float* __restrict__ features,
        float* __restrict__ out) {
    GEMM256_PRE;
    int tile = xcd_map(blockIdx.x, gridDim.x);   // 391*2 blocks
    int rt = tile >> 1, ct = tile & 1;
    int rowbase = rt * 256, colbase = ct * 256;
    gemm256<8>(tbuf + (size_t)rowbase * DIM, DIM,
               wov + (size_t)colbase * DIM, DIM, As, Bs, acc);
    #pragma unroll
    for (int m = 0; m < 8; ++m)
        #pragma unroll
        for (int n = 0; n < 4; ++n)
            #pragma unroll
            for (int rr = 0; rr < 4; ++rr) {
                int orow = rowbase + wr * 128 + m * 16 + ks * 4 + rr;
                int ocol = colbase + wc * 64 + n * 16 + r;
                if (orow < NPTS) {
                    out[(size_t)orow * DIM + ocol] =
                        acc[m][n][rr] + bo[ocol] + features[(size_t)orow * DIM + ocol];
                }
            }
}

// ---------------- FFN1: h = gelu(y @ W1.T + b1), bf16 out, N=1024 --------------------
__global__ __launch_bounds__(512) void ffn1_kernel(
        const short* __restrict__ y, const short* __restrict__ w1,
        const float* __restrict__ b1, short* __restrict__ h) {
    GEMM256_PRE;
    int tile = xcd_map(blockIdx.x, gridDim.x);   // 391*4 blocks
    int rt = tile >> 2, ct = tile & 3;
    int rowbase = rt * 256, colbase = ct * 256;
    gemm256<8>(y + (size_t)rowbase * DIM, DIM,
               w1 + (size_t)colbase * DIM, DIM, As, Bs, acc);
    #pragma unroll
    for (int m = 0; m < 8; ++m)
        #pragma unroll
        for (int n = 0; n < 4; ++n)
            #pragma unroll
            for (int rr = 0; rr < 4; ++rr) {
                int orow = rowbase + wr * 128 + m * 16 + ks * 4 + rr;
                int ocol = colbase + wc * 64 + n * 16 + r;
                float xv = acc[m][n][rr] + b1[ocol];
                // exact-GELU via clamped tanh form (max abs err ~3e-3)
                float xc = fminf(fmaxf(xv, -9.0f), 9.0f);
                float u = xc * (0.7978845608028654f + 0.0356774081f * xc * xc);
                float e2 = __expf(2.0f * u);
                float th = (e2 - 1.0f) / (e2 + 1.0f);
                float gl = 0.5f * xv * (1.0f + th);
                h[(size_t)orow * (2 * DIM) + ocol] = f2bf(gl);
            }
}

// ---------------- FFN2: d_out = h @ W2.T + b2 + d_out(res2), K=1024 ------------------
__global__ __launch_bounds__(512) void ffn2_kernel(
        const short* __restrict__ h, const short* __restrict__ w2,
        const float* __restrict__ b2, float* __restrict__ out) {
    GEMM256_PRE;
    int tile = xcd_map(blockIdx.x, gridDim.x);   // 391*2 blocks
    int rt = tile >> 1, ct = tile & 1;
    int rowbase = rt * 256, colbase = ct * 256;
    gemm256<16>(h + (size_t)rowbase * (2 * DIM), 2 * DIM,
                w2 + (size_t)colbase * (2 * DIM), 2 * DIM, As, Bs, acc);
    #pragma unroll
    for (int m = 0; m < 8; ++m)
        #pragma unroll
        for (int n = 0; n < 4; ++n)
            #pragma unroll
            for (int rr = 0; rr < 4; ++rr) {
                int orow = rowbase + wr * 128 + m * 16 + ks * 4 + rr;
                int ocol = colbase + wc * 64 + n * 16 + r;
                if (orow < NPTS) {
                    size_t idx = (size_t)orow * DIM + ocol;
                    out[idx] = acc[m][n][rr] + b2[ocol] + out[idx];
                }
            }
}

extern "C" void kernel_launch(void* const* d_in, const int* in_sizes, int n_in,
                              void* d_out, int out_size, void* d_ws, size_t ws_size,
                              hipStream_t stream) {
    const float* features = (const float*)d_in[0];
    const int*   neighbors = (const int*)d_in[2];
    const float* Wq = (const float*)d_in[3];
    const float* Wk = (const float*)d_in[4];
    const float* Wv = (const float*)d_in[5];
    const float* Wo = (const float*)d_in[6];
    const float* bo = (const float*)d_in[7];
    const float* ln1_g = (const float*)d_in[8];
    const float* ln1_b = (const float*)d_in[9];
    const float* ln2_g = (const float*)d_in[10];
    const float* ln2_b = (const float*)d_in[11];
    const float* W1 = (const float*)d_in[12];
    const float* b1 = (const float*)d_in[13];
    const float* W2 = (const float*)d_in[14];
    const float* b2 = (const float*)d_in[15];
    float* out = (float*)d_out;

    size_t slotElems = (size_t)PAD_ROWS * DIM;
    short* s0 = (short*)d_ws;            // x (ln1) -> y (ln2)
    short* s1 = s0 + slotElems;          // q' -> h (low half; s1+s2 contiguous = h[PAD][1024])
    short* s2 = s1 + slotElems;          // t  -> h (high half)
    short* mt_b  = s2 + slotElems;       // 4*128*128
    short* wov_b = mt_b + GRP * GD * GD; // 512*512
    short* w1_b  = wov_b + DIM * DIM;    // 1024*512
    short* w2_b  = w1_b + 2 * DIM * DIM; // 512*1024

    cvt_kernel<<<256, 256, 0, stream>>>(W1, w1_b, 2 * DIM * DIM);
    cvt_kernel<<<256, 256, 0, stream>>>(W2, w2_b, 2 * DIM * DIM);
    prep_m_kernel<<<GRP * GD, GD, 0, stream>>>(Wq, Wk, mt_b);
    prep_wov_kernel<<<DIM, DIM, 0, stream>>>(Wo, Wv, wov_b);

    // LN1: features -> x (bf16), zero-padded rows
    ln_kernel<<<PAD_ROWS, 128, 0, stream>>>(features, ln1_g, ln1_b, s0);

    // q' = Mt x (single grouped GEMM pass, 128^2 core)
    qproj_kernel<<<(PAD_ROWS / 128) * 4, 256, 0, stream>>>(s0, mt_b, s1);

    // attention: gather x only -> t in s2
    attn_kernel<<<NPTS, 256, 0, stream>>>(s1, s0, neighbors, s2);

    // out = t @ Wov.T + bo + features  (f32, in d_out)  [256^2 swizzled core]
    outproj_kernel<<<(PAD_ROWS / 256) * 2, 512, 0, stream>>>(s2, wov_b, bo, features, out);

    // LN2: d_out -> y (bf16) in s0
    ln_kernel<<<PAD_ROWS, 128, 0, stream>>>(out, ln2_g, ln2_b, s0);

    // FFN1: h = gelu(y @ W1.T + b1) -> s1..s2 region (PAD x 1024 bf16)  [256^2 core]
    ffn1_kernel<<<(PAD_ROWS / 256) * 4, 512, 0, stream>>>(s0, w1_b, b1, s1);

    // FFN2: d_out = h @ W2.T + b2 + d_out  [256^2 core]
    ffn2_kernel<<<(PAD_ROWS / 256) * 2, 512, 0, stream>>>(s1, w2_b, b2, out);
}

// Round 10
// 1304.245 us; speedup vs baseline: 1.2104x; 1.0171x over previous
//
#include <hip/hip_runtime.h>
#include <hip/hip_bf16.h>
#include <math.h>

#define NPTS 100000
#define PAD_ROWS 100096   // 391 * 256
#define DIM 512
#define GRP 4
#define GD 128
#define K_NBR 16
#define EPS 1e-5f

using bf16x8 = __attribute__((ext_vector_type(8))) short;
using f32x4  = __attribute__((ext_vector_type(4))) float;
using short4v = __attribute__((ext_vector_type(4))) short;

__device__ inline float bf2f(short s) {
    unsigned u = ((unsigned)(unsigned short)s) << 16;
    union { unsigned u; float f; } c; c.u = u; return c.f;
}
__device__ inline short f2bf(float f) {
    union { float f; unsigned u; } c; c.f = f;
    unsigned u = c.u;
    unsigned r = (u + 0x7fffu + ((u >> 16) & 1u)) >> 16;
    return (short)r;
}

__device__ __forceinline__ void gload_lds16(short* lds, const short* g) {
    __builtin_amdgcn_global_load_lds(
        (const __attribute__((address_space(1))) unsigned int*)g,
        (__attribute__((address_space(3))) unsigned int*)lds, 16, 0, 0);
}

// bijective XCD swizzle (m204): works for nwg % 8 != 0
__device__ __forceinline__ int xcd_map(int bid, int nwg) {
    int q = nwg >> 3, r8 = nwg & 7;
    int xcd = bid & 7, idx = bid >> 3;
    int base = (xcd < r8) ? xcd * (q + 1) : r8 * (q + 1) + (xcd - r8) * q;
    return base + idx;
}

// ---------------- weight convert f32 -> bf16 ----------------
__global__ void cvt_kernel(const float* __restrict__ src, short* __restrict__ dst, int n) {
    int i = blockIdx.x * blockDim.x + threadIdx.x;
    int stride = gridDim.x * blockDim.x;
    for (; i < n; i += stride) dst[i] = f2bf(src[i]);
}

// ---------------- Mt[g][e][d] = scale * sum_o Wq[g][o][d] * Wk[g][o][e] --------------
__global__ void prep_m_kernel(const float* __restrict__ wq, const float* __restrict__ wk,
                              short* __restrict__ mt) {
    int ge = blockIdx.x;            // g*128 + e
    int g = ge >> 7, e = ge & 127;
    int d = threadIdx.x;            // 128 threads
    const float* Wq = wq + (size_t)g * GD * GD;
    const float* Wk = wk + (size_t)g * GD * GD;
    float acc = 0.0f;
    for (int o = 0; o < GD; ++o)
        acc += Wq[(size_t)o * GD + d] * Wk[(size_t)o * GD + e];
    mt[(size_t)ge * GD + d] = f2bf(acc * 0.08838834764831845f);
}

// ---------------- Wov[o][g*128+i0] = sum_d Wo[o][g*128+d] * Wv[g][d][i0] -------------
__global__ void prep_wov_kernel(const float* __restrict__ wo, const float* __restrict__ wv,
                                short* __restrict__ wov) {
    int o = blockIdx.x;             // 512 blocks
    int i = threadIdx.x;            // 512 threads
    int g = i >> 7, i0 = i & 127;
    float acc = 0.0f;
    for (int d = 0; d < GD; ++d)
        acc += wo[(size_t)o * DIM + g * GD + d] * wv[((size_t)g * GD + d) * GD + i0];
    wov[(size_t)o * DIM + i] = f2bf(acc);
}

// ---------------- LayerNorm (f32 in -> bf16 out) ----------------
__global__ void ln_kernel(const float* __restrict__ in, const float* __restrict__ g,
                          const float* __restrict__ b, short* __restrict__ out) {
    int row = blockIdx.x;
    int tid = threadIdx.x; // 128 threads, 4 elems each
    if (row >= NPTS) {
        short4v z; z[0] = 0; z[1] = 0; z[2] = 0; z[3] = 0;
        *(short4v*)(out + (size_t)row * DIM + tid * 4) = z;
        return;
    }
    const float4 x = *(const float4*)(in + (size_t)row * DIM + tid * 4);
    float s  = x.x + x.y + x.z + x.w;
    float sq = x.x * x.x + x.y * x.y + x.z * x.z + x.w * x.w;
    for (int m = 1; m < 64; m <<= 1) {
        s  += __shfl_xor(s, m);
        sq += __shfl_xor(sq, m);
    }
    __shared__ float ss[2], ssq[2];
    int wv = tid >> 6;
    if ((tid & 63) == 0) { ss[wv] = s; ssq[wv] = sq; }
    __syncthreads();
    s = ss[0] + ss[1]; sq = ssq[0] + ssq[1];
    float mu = s * (1.0f / DIM);
    float var = sq * (1.0f / DIM) - mu * mu;
    float rstd = rsqrtf(var + EPS);
    const float4 gg = *(const float4*)(g + tid * 4);
    const float4 bb = *(const float4*)(b + tid * 4);
    short4v o;
    o[0] = f2bf((x.x - mu) * rstd * gg.x + bb.x);
    o[1] = f2bf((x.y - mu) * rstd * gg.y + bb.y);
    o[2] = f2bf((x.z - mu) * rstd * gg.z + bb.z);
    o[3] = f2bf((x.w - mu) * rstd * gg.w + bb.w);
    *(short4v*)(out + (size_t)row * DIM + tid * 4) = o;
}

// ===== 256x256 GEMM core, BK=32, 4-deep pipelined (T4 counted vmcnt), 8 waves ========
// Per iter: stage(t+3) -> s_waitcnt vmcnt(12) -> s_barrier -> compute(t) -> s_barrier.
// 3 tiles x 4 gload_lds/wave stay in flight across barriers (never drain to 0 in loop).
// Race audit: stage(t+3) overwrites buf[(t-1)&3]; legal since post-compute barrier of
// iter t-1 was passed by all waves. Data-ready: every wave waits own vmcnt pre-barrier.
#define PBK 32
#define PBUF (256 * PBK)              // 8192 shorts = 16 KB per A or B buffer
// LDS total: 4 bufs * (A+B) * 16 KB = 128 KB

__device__ __forceinline__ void stageP(short* As, short* Bs,
        const short* aS, int as_, const short* bS, int bs_, int tid) {
    int row = tid >> 2;              // 0..127
    int col = (tid & 3) * 8;         // elem col within BK=32
    gload_lds16(As + row * 32 + col,         aS + (size_t)row * as_ + col);
    gload_lds16(As + (row + 128) * 32 + col, aS + (size_t)(row + 128) * as_ + col);
    gload_lds16(Bs + row * 32 + col,         bS + (size_t)row * bs_ + col);
    gload_lds16(Bs + (row + 128) * 32 + col, bS + (size_t)(row + 128) * bs_ + col);
}

__device__ __forceinline__ void computeP(const short* As, const short* Bs,
        int wr, int wc, int r, int ks, f32x4 (&acc)[8][4]) {
    bf16x8 a[8];
    #pragma unroll
    for (int m = 0; m < 8; ++m)
        a[m] = *(const bf16x8*)(As + (wr * 128 + m * 16 + r) * 32 + ks * 8);
    #pragma unroll
    for (int n = 0; n < 4; ++n) {
        bf16x8 b = *(const bf16x8*)(Bs + (wc * 64 + n * 16 + r) * 32 + ks * 8);
        #pragma unroll
        for (int m = 0; m < 8; ++m)
            acc[m][n] = __builtin_amdgcn_mfma_f32_16x16x32_bf16(a[m], b, acc[m][n], 0, 0, 0);
    }
}

template<int NT>
__device__ __forceinline__ void gemmP(
        const short* __restrict__ aBase, int as_,
        const short* __restrict__ bBase, int bs_,
        short* P, f32x4 (&acc)[8][4]) {
    int tid = threadIdx.x;
    int lane = tid & 63, wave = tid >> 6;
    int wr = wave >> 2, wc = wave & 3;
    int r = lane & 15, ks = lane >> 4;
    // prologue: 3 tiles in flight (12 loads/wave)
    stageP(P,                P + PBUF,                aBase,           as_, bBase,           bs_, tid);
    stageP(P + 2 * PBUF,     P + 3 * PBUF,            aBase + PBK,     as_, bBase + PBK,     bs_, tid);
    stageP(P + 4 * PBUF,     P + 5 * PBUF,            aBase + 2 * PBK, as_, bBase + 2 * PBK, bs_, tid);
    for (int t = 0; t < NT; ++t) {
        short* Ab = P + (t & 3) * (2 * PBUF);
        if (t + 3 < NT) {
            short* An = P + ((t + 3) & 3) * (2 * PBUF);
            stageP(An, An + PBUF, aBase + (size_t)(t + 3) * PBK, as_,
                   bBase + (size_t)(t + 3) * PBK, bs_, tid);
            asm volatile("s_waitcnt vmcnt(12)" ::: "memory");
        } else if (t + 2 < NT) {
            asm volatile("s_waitcnt vmcnt(8)" ::: "memory");
        } else if (t + 1 < NT) {
            asm volatile("s_waitcnt vmcnt(4)" ::: "memory");
        } else {
            asm volatile("s_waitcnt vmcnt(0)" ::: "memory");
        }
        __builtin_amdgcn_s_barrier();
        __builtin_amdgcn_sched_barrier(0);
        computeP(Ab, Ab + PBUF, wr, wc, r, ks, acc);
        __builtin_amdgcn_s_barrier();
    }
}

#define GEMMP_PRE \
    __shared__ short P[8 * PBUF]; \
    int tid = threadIdx.x; \
    int lane = tid & 63, wave = tid >> 6; \
    int wr = wave >> 2, wc = wave & 3; \
    int r = lane & 15, ks = lane >> 4; \
    f32x4 acc[8][4]; \
    _Pragma("unroll") \
    for (int m = 0; m < 8; ++m) \
        _Pragma("unroll") \
        for (int n = 0; n < 4; ++n) \
            _Pragma("unroll") \
            for (int e = 0; e < 4; ++e) acc[m][n][e] = 0.0f;

// ---------------- old 128x128 core (kept for qproj, K=128) ---------------------------
__device__ __forceinline__ void stage_tile(short* As, short* Bs,
        const short* aS, int as_, const short* bS, int bs_, int tid) {
    int ldRow = tid >> 2;
    int ldCol = (tid & 3) * 8;
    gload_lds16(As + (ldRow)      * 32 + ldCol, aS + (size_t)(ldRow)      * as_ + ldCol);
    gload_lds16(As + (ldRow + 64) * 32 + ldCol, aS + (size_t)(ldRow + 64) * as_ + ldCol);
    gload_lds16(Bs + (ldRow)      * 32 + ldCol, bS + (size_t)(ldRow)      * bs_ + ldCol);
    gload_lds16(Bs + (ldRow + 64) * 32 + ldCol, bS + (size_t)(ldRow + 64) * bs_ + ldCol);
}

__device__ __forceinline__ void compute_tile(const short* As, const short* Bs,
        int wr, int wc, int r, int ks, f32x4 (&acc)[4][4]) {
    bf16x8 a[4];
    #pragma unroll
    for (int m = 0; m < 4; ++m)
        a[m] = *(const bf16x8*)(As + (wr * 64 + m * 16 + r) * 32 + ks * 8);
    #pragma unroll
    for (int n = 0; n < 4; ++n) {
        bf16x8 b = *(const bf16x8*)(Bs + (wc * 64 + n * 16 + r) * 32 + ks * 8);
        #pragma unroll
        for (int m = 0; m < 4; ++m)
            acc[m][n] = __builtin_amdgcn_mfma_f32_16x16x32_bf16(a[m], b, acc[m][n], 0, 0, 0);
    }
}

template<int NK>
__device__ __forceinline__ void gemm_tile(
        const short* __restrict__ aBase, int as_,
        const short* __restrict__ bBase, int bs_,
        short* As0, short* Bs0, short* As1, short* Bs1, f32x4 (&acc)[4][4]) {
    int tid = threadIdx.x;
    int lane = tid & 63, wave = tid >> 6;
    int wr = wave >> 1, wc = wave & 1;
    int r = lane & 15, ks = lane >> 4;
    stage_tile(As0, Bs0, aBase, as_, bBase, bs_, tid);
    __syncthreads();
    #pragma unroll
    for (int kt = 0; kt < NK; kt += 2) {
        if (kt + 1 < NK)
            stage_tile(As1, Bs1, aBase + (kt + 1) * 32, as_, bBase + (kt + 1) * 32, bs_, tid);
        compute_tile(As0, Bs0, wr, wc, r, ks, acc);
        __syncthreads();
        if (kt + 2 < NK)
            stage_tile(As0, Bs0, aBase + (kt + 2) * 32, as_, bBase + (kt + 2) * 32, bs_, tid);
        compute_tile(As1, Bs1, wr, wc, r, ks, acc);
        __syncthreads();
    }
}

// ---------------- q' projection: q'[n][g*128+e] = sum_d x[n][g*128+d] * Mt[g][e][d] ---
__global__ __launch_bounds__(256) void qproj_kernel(
        const short* __restrict__ x, const short* __restrict__ mt,
        short* __restrict__ qp) {
    __shared__ short As0[128 * 32], Bs0[128 * 32], As1[128 * 32], Bs1[128 * 32];
    int nwg = gridDim.x;
    int bid = blockIdx.x;
    int tile = xcd_map(bid, nwg);
    int rb = tile >> 2, g = tile & 3;
    int rowbase = rb * 128;
    int tid = threadIdx.x;
    int lane = tid & 63, wave = tid >> 6;
    int wr = wave >> 1, wc = wave & 1;
    int r = lane & 15, ks = lane >> 4;
    f32x4 acc[4][4];
    #pragma unroll
    for (int m = 0; m < 4; ++m)
        #pragma unroll
        for (int n = 0; n < 4; ++n)
            #pragma unroll
            for (int e = 0; e < 4; ++e) acc[m][n][e] = 0.0f;
    gemm_tile<4>(x + (size_t)rowbase * DIM + g * GD, DIM,
                 mt + (size_t)g * GD * GD, GD, As0, Bs0, As1, Bs1, acc);
    #pragma unroll
    for (int m = 0; m < 4; ++m)
        #pragma unroll
        for (int n = 0; n < 4; ++n)
            #pragma unroll
            for (int rr = 0; rr < 4; ++rr) {
                int orow = rowbase + wr * 64 + m * 16 + ks * 4 + rr;
                int lcol = wc * 64 + n * 16 + r;
                qp[(size_t)orow * DIM + g * GD + lcol] = f2bf(acc[m][n][rr]);
            }
}

// ---------------- attention: gathers x only; t[n][g] = sum_j softmax_j * x_j[g-slice] -
__global__ __launch_bounds__(256) void attn_kernel(
        const short* __restrict__ qp, const short* __restrict__ x,
        const int* __restrict__ nbrs, short* __restrict__ t_out) {
    int b = blockIdx.x;
    int xcd = b & 7;
    int g = xcd >> 1;
    int quad = (b >> 3) * 2 + (xcd & 1);   // 0..24999
    int tid = threadIdx.x;
    int wv = tid >> 6, lane = tid & 63;
    int n = quad * 4 + wv;                 // 0..99999
    int s = lane >> 4, t = lane & 15;
    int4 nbj = *(const int4*)(nbrs + (size_t)n * K_NBR + s * 4);
    int nbarr[4] = {nbj.x, nbj.y, nbj.z, nbj.w};
    size_t goff = (size_t)g * GD + t * 8;
    size_t qbase = (size_t)n * DIM + goff;
    bf16x8 qf = *(const bf16x8*)(qp + qbase);
    float qv[8];
    #pragma unroll
    for (int e = 0; e < 8; ++e) qv[e] = bf2f(qf[e]);
    bf16x8 xf[4];
    #pragma unroll
    for (int p = 0; p < 4; ++p)
        xf[p] = *(const bf16x8*)(x + (size_t)nbarr[p] * DIM + goff);
    float sc[4];
    #pragma unroll
    for (int p = 0; p < 4; ++p) {
        float dd = 0.0f;
        #pragma unroll
        for (int e = 0; e < 8; ++e) dd += qv[e] * bf2f(xf[p][e]);
        dd += __shfl_xor(dd, 1);
        dd += __shfl_xor(dd, 2);
        dd += __shfl_xor(dd, 4);
        dd += __shfl_xor(dd, 8);
        sc[p] = dd;
    }
    float mx = fmaxf(fmaxf(sc[0], sc[1]), fmaxf(sc[2], sc[3]));
    mx = fmaxf(mx, __shfl_xor(mx, 16));
    mx = fmaxf(mx, __shfl_xor(mx, 32));
    float ew[4]; float ssum = 0.0f;
    #pragma unroll
    for (int p = 0; p < 4; ++p) { ew[p] = __expf(sc[p] - mx); ssum += ew[p]; }
    ssum += __shfl_xor(ssum, 16);
    ssum += __shfl_xor(ssum, 32);
    float acc[8];
    #pragma unroll
    for (int d0 = 0; d0 < 8; ++d0) acc[d0] = 0.0f;
    #pragma unroll
    for (int p = 0; p < 4; ++p) {
        #pragma unroll
        for (int d0 = 0; d0 < 8; ++d0) acc[d0] += ew[p] * bf2f(xf[p][d0]);
    }
    #pragma unroll
    for (int d0 = 0; d0 < 8; ++d0) {
        acc[d0] += __shfl_xor(acc[d0], 16);
        acc[d0] += __shfl_xor(acc[d0], 32);
    }
    if (s == 0) {
        float inv = 1.0f / ssum;
        bf16x8 o;
        #pragma unroll
        for (int d0 = 0; d0 < 8; ++d0) o[d0] = f2bf(acc[d0] * inv);
        *(bf16x8*)(t_out + qbase) = o;
    }
}

// ---------------- out = t @ Wov.T + bo + features (residual) -> f32 d_out -------------
__global__ __launch_bounds__(512) void outproj_kernel(
        const short* __restrict__ tbuf, const short* __restrict__ wov,
        const float* __restrict__ bo, const float* __restrict__ features,
        float* __restrict__ out) {
    GEMMP_PRE;
    int tile = xcd_map(blockIdx.x, gridDim.x);   // 391*2 blocks
    int rt = tile >> 1, ct = tile & 1;
    int rowbase = rt * 256, colbase = ct * 256;
    gemmP<16>(tbuf + (size_t)rowbase * DIM, DIM,
              wov + (size_t)colbase * DIM, DIM, P, acc);
    #pragma unroll
    for (int m = 0; m < 8; ++m)
        #pragma unroll
        for (int n = 0; n < 4; ++n)
            #pragma unroll
            for (int rr = 0; rr < 4; ++rr) {
                int orow = rowbase + wr * 128 + m * 16 + ks * 4 + rr;
                int ocol = colbase + wc * 64 + n * 16 + r;
                if (orow < NPTS) {
                    out[(size_t)orow * DIM + ocol] =
                        acc[m][n][rr] + bo[ocol] + features[(size_t)orow * DIM + ocol];
                }
            }
}

// ---------------- FFN1: h = gelu(y @ W1.T + b1), bf16 out, N=1024 --------------------
__global__ __launch_bounds__(512) void ffn1_kernel(
        const short* __restrict__ y, const short* __restrict__ w1,
        const float* __restrict__ b1, short* __restrict__ h) {
    GEMMP_PRE;
    int tile = xcd_map(blockIdx.x, gridDim.x);   // 391*4 blocks
    int rt = tile >> 2, ct = tile & 3;
    int rowbase = rt * 256, colbase = ct * 256;
    gemmP<16>(y + (size_t)rowbase * DIM, DIM,
              w1 + (size_t)colbase * DIM, DIM, P, acc);
    #pragma unroll
    for (int m = 0; m < 8; ++m)
        #pragma unroll
        for (int n = 0; n < 4; ++n)
            #pragma unroll
            for (int rr = 0; rr < 4; ++rr) {
                int orow = rowbase + wr * 128 + m * 16 + ks * 4 + rr;
                int ocol = colbase + wc * 64 + n * 16 + r;
                float xv = acc[m][n][rr] + b1[ocol];
                // exact-GELU via clamped tanh form (max abs err ~3e-3)
                float xc = fminf(fmaxf(xv, -9.0f), 9.0f);
                float u = xc * (0.7978845608028654f + 0.0356774081f * xc * xc);
                float e2 = __expf(2.0f * u);
                float th = (e2 - 1.0f) / (e2 + 1.0f);
                float gl = 0.5f * xv * (1.0f + th);
                h[(size_t)orow * (2 * DIM) + ocol] = f2bf(gl);
            }
}

// ---------------- FFN2: d_out = h @ W2.T + b2 + d_out(res2), K=1024 ------------------
__global__ __launch_bounds__(512) void ffn2_kernel(
        const short* __restrict__ h, const short* __restrict__ w2,
        const float* __restrict__ b2, float* __restrict__ out) {
    GEMMP_PRE;
    int tile = xcd_map(blockIdx.x, gridDim.x);   // 391*2 blocks
    int rt = tile >> 1, ct = tile & 1;
    int rowbase = rt * 256, colbase = ct * 256;
    gemmP<32>(h + (size_t)rowbase * (2 * DIM), 2 * DIM,
              w2 + (size_t)colbase * (2 * DIM), 2 * DIM, P, acc);
    #pragma unroll
    for (int m = 0; m < 8; ++m)
        #pragma unroll
        for (int n = 0; n < 4; ++n)
            #pragma unroll
            for (int rr = 0; rr < 4; ++rr) {
                int orow = rowbase + wr * 128 + m * 16 + ks * 4 + rr;
                int ocol = colbase + wc * 64 + n * 16 + r;
                if (orow < NPTS) {
                    size_t idx = (size_t)orow * DIM + ocol;
                    out[idx] = acc[m][n][rr] + b2[ocol] + out[idx];
                }
            }
}

extern "C" void kernel_launch(void* const* d_in, const int* in_sizes, int n_in,
                              void* d_out, int out_size, void* d_ws, size_t ws_size,
                              hipStream_t stream) {
    const float* features = (const float*)d_in[0];
    const int*   neighbors = (const int*)d_in[2];
    const float* Wq = (const float*)d_in[3];
    const float* Wk = (const float*)d_in[4];
    const float* Wv = (const float*)d_in[5];
    const float* Wo = (const float*)d_in[6];
    const float* bo = (const float*)d_in[7];
    const float* ln1_g = (const float*)d_in[8];
    const float* ln1_b = (const float*)d_in[9];
    const float* ln2_g = (const float*)d_in[10];
    const float* ln2_b = (const float*)d_in[11];
    const float* W1 = (const float*)d_in[12];
    const float* b1 = (const float*)d_in[13];
    const float* W2 = (const float*)d_in[14];
    const float* b2 = (const float*)d_in[15];
    float* out = (float*)d_out;

    size_t slotElems = (size_t)PAD_ROWS * DIM;
    short* s0 = (short*)d_ws;            // x (ln1) -> y (ln2)
    short* s1 = s0 + slotElems;          // q' -> h (low half; s1+s2 contiguous = h[PAD][1024])
    short* s2 = s1 + slotElems;          // t  -> h (high half)
    short* mt_b  = s2 + slotElems;       // 4*128*128
    short* wov_b = mt_b + GRP * GD * GD; // 512*512
    short* w1_b  = wov_b + DIM * DIM;    // 1024*512
    short* w2_b  = w1_b + 2 * DIM * DIM; // 512*1024

    cvt_kernel<<<256, 256, 0, stream>>>(W1, w1_b, 2 * DIM * DIM);
    cvt_kernel<<<256, 256, 0, stream>>>(W2, w2_b, 2 * DIM * DIM);
    prep_m_kernel<<<GRP * GD, GD, 0, stream>>>(Wq, Wk, mt_b);
    prep_wov_kernel<<<DIM, DIM, 0, stream>>>(Wo, Wv, wov_b);

    // LN1: features -> x (bf16), zero-padded rows
    ln_kernel<<<PAD_ROWS, 128, 0, stream>>>(features, ln1_g, ln1_b, s0);

    // q' = Mt x (single grouped GEMM pass, 128^2 core)
    qproj_kernel<<<(PAD_ROWS / 128) * 4, 256, 0, stream>>>(s0, mt_b, s1);

    // attention: gather x only -> t in s2
    attn_kernel<<<NPTS, 256, 0, stream>>>(s1, s0, neighbors, s2);

    // out = t @ Wov.T + bo + features  (f32, in d_out)  [pipelined 256^2 core]
    outproj_kernel<<<(PAD_ROWS / 256) * 2, 512, 0, stream>>>(s2, wov_b, bo, features, out);

    // LN2: d_out -> y (bf16) in s0
    ln_kernel<<<PAD_ROWS, 128, 0, stream>>>(out, ln2_g, ln2_b, s0);

    // FFN1: h = gelu(y @ W1.T + b1) -> s1..s2 region (PAD x 1024 bf16)  [pipelined]
    ffn1_kernel<<<(PAD_ROWS / 256) * 4, 512, 0, stream>>>(s0, w1_b, b1, s1);

    // FFN2: d_out = h @ W2.T + b2 + d_out  [pipelined]
    ffn2_kernel<<<(PAD_ROWS / 256) * 2, 512, 0, stream>>>(s1, w2_b, b2, out);
}

// Round 11
// 1072.145 us; speedup vs baseline: 1.4724x; 1.2165x over previous
//
#include <hip/hip_runtime.h>
#include <hip/hip_bf16.h>
#include <math.h>

#define NPTS 100000
#define PAD_ROWS 100096   // 782 * 128
#define DIM 512
#define GRP 4
#define GD 128
#define K_NBR 16
#define EPS 1e-5f

using bf16x8 = __attribute__((ext_vector_type(8))) short;
using f32x4  = __attribute__((ext_vector_type(4))) float;
using short4v = __attribute__((ext_vector_type(4))) short;

__device__ inline float bf2f(short s) {
    unsigned u = ((unsigned)(unsigned short)s) << 16;
    union { unsigned u; float f; } c; c.u = u; return c.f;
}
__device__ inline short f2bf(float f) {
    union { float f; unsigned u; } c; c.f = f;
    unsigned u = c.u;
    unsigned r = (u + 0x7fffu + ((u >> 16) & 1u)) >> 16;
    return (short)r;
}

__device__ __forceinline__ void gload_lds16(short* lds, const short* g) {
    __builtin_amdgcn_global_load_lds(
        (const __attribute__((address_space(1))) unsigned int*)g,
        (__attribute__((address_space(3))) unsigned int*)lds, 16, 0, 0);
}

// ---------------- weight convert f32 -> bf16 ----------------
__global__ void cvt_kernel(const float* __restrict__ src, short* __restrict__ dst, int n) {
    int i = blockIdx.x * blockDim.x + threadIdx.x;
    int stride = gridDim.x * blockDim.x;
    for (; i < n; i += stride) dst[i] = f2bf(src[i]);
}

// ---------------- Mt[g][e][d] = scale * sum_o Wq[g][o][d] * Wk[g][o][e] --------------
__global__ void prep_m_kernel(const float* __restrict__ wq, const float* __restrict__ wk,
                              short* __restrict__ mt) {
    int ge = blockIdx.x;            // g*128 + e
    int g = ge >> 7, e = ge & 127;
    int d = threadIdx.x;            // 128 threads
    const float* Wq = wq + (size_t)g * GD * GD;
    const float* Wk = wk + (size_t)g * GD * GD;
    float acc = 0.0f;
    for (int o = 0; o < GD; ++o)
        acc += Wq[(size_t)o * GD + d] * Wk[(size_t)o * GD + e];
    mt[(size_t)ge * GD + d] = f2bf(acc * 0.08838834764831845f);
}

// ---------------- Wov[o][g*128+i0] = sum_d Wo[o][g*128+d] * Wv[g][d][i0] -------------
__global__ void prep_wov_kernel(const float* __restrict__ wo, const float* __restrict__ wv,
                                short* __restrict__ wov) {
    int o = blockIdx.x;             // 512 blocks
    int i = threadIdx.x;            // 512 threads
    int g = i >> 7, i0 = i & 127;
    float acc = 0.0f;
    for (int d = 0; d < GD; ++d)
        acc += wo[(size_t)o * DIM + g * GD + d] * wv[((size_t)g * GD + d) * GD + i0];
    wov[(size_t)o * DIM + i] = f2bf(acc);
}

// ---------------- LayerNorm (f32 in -> bf16 out) ----------------
__global__ void ln_kernel(const float* __restrict__ in, const float* __restrict__ g,
                          const float* __restrict__ b, short* __restrict__ out) {
    int row = blockIdx.x;
    int tid = threadIdx.x; // 128 threads, 4 elems each
    if (row >= NPTS) {
        short4v z; z[0] = 0; z[1] = 0; z[2] = 0; z[3] = 0;
        *(short4v*)(out + (size_t)row * DIM + tid * 4) = z;
        return;
    }
    const float4 x = *(const float4*)(in + (size_t)row * DIM + tid * 4);
    float s  = x.x + x.y + x.z + x.w;
    float sq = x.x * x.x + x.y * x.y + x.z * x.z + x.w * x.w;
    for (int m = 1; m < 64; m <<= 1) {
        s  += __shfl_xor(s, m);
        sq += __shfl_xor(sq, m);
    }
    __shared__ float ss[2], ssq[2];
    int wv = tid >> 6;
    if ((tid & 63) == 0) { ss[wv] = s; ssq[wv] = sq; }
    __syncthreads();
    s = ss[0] + ss[1]; sq = ssq[0] + ssq[1];
    float mu = s * (1.0f / DIM);
    float var = sq * (1.0f / DIM) - mu * mu;
    float rstd = rsqrtf(var + EPS);
    const float4 gg = *(const float4*)(g + tid * 4);
    const float4 bb = *(const float4*)(b + tid * 4);
    short4v o;
    o[0] = f2bf((x.x - mu) * rstd * gg.x + bb.x);
    o[1] = f2bf((x.y - mu) * rstd * gg.y + bb.y);
    o[2] = f2bf((x.z - mu) * rstd * gg.z + bb.z);
    o[3] = f2bf((x.w - mu) * rstd * gg.w + bb.w);
    *(short4v*)(out + (size_t)row * DIM + tid * 4) = o;
}

// ---------------- LayerNorm (bf16 in -> bf16 out), for res2 ----------------
__global__ void ln_bf16_kernel(const short* __restrict__ in, const float* __restrict__ g,
                               const float* __restrict__ b, short* __restrict__ out) {
    int row = blockIdx.x;
    int tid = threadIdx.x; // 128 threads, 4 elems each
    if (row >= NPTS) {
        short4v z; z[0] = 0; z[1] = 0; z[2] = 0; z[3] = 0;
        *(short4v*)(out + (size_t)row * DIM + tid * 4) = z;
        return;
    }
    short4v xi = *(const short4v*)(in + (size_t)row * DIM + tid * 4);
    float x0 = bf2f(xi[0]), x1 = bf2f(xi[1]), x2 = bf2f(xi[2]), x3 = bf2f(xi[3]);
    float s  = x0 + x1 + x2 + x3;
    float sq = x0 * x0 + x1 * x1 + x2 * x2 + x3 * x3;
    for (int m = 1; m < 64; m <<= 1) {
        s  += __shfl_xor(s, m);
        sq += __shfl_xor(sq, m);
    }
    __shared__ float ss[2], ssq[2];
    int wv = tid >> 6;
    if ((tid & 63) == 0) { ss[wv] = s; ssq[wv] = sq; }
    __syncthreads();
    s = ss[0] + ss[1]; sq = ssq[0] + ssq[1];
    float mu = s * (1.0f / DIM);
    float var = sq * (1.0f / DIM) - mu * mu;
    float rstd = rsqrtf(var + EPS);
    const float4 gg = *(const float4*)(g + tid * 4);
    const float4 bb = *(const float4*)(b + tid * 4);
    short4v o;
    o[0] = f2bf((x0 - mu) * rstd * gg.x + bb.x);
    o[1] = f2bf((x1 - mu) * rstd * gg.y + bb.y);
    o[2] = f2bf((x2 - mu) * rstd * gg.z + bb.z);
    o[3] = f2bf((x3 - mu) * rstd * gg.w + bb.w);
    *(short4v*)(out + (size_t)row * DIM + tid * 4) = o;
}

// ---------------- 128x128 GEMM core, BK=32, 2-phase double-buffered ------------------
__device__ __forceinline__ void stage_tile(short* As, short* Bs,
        const short* aS, int as_, const short* bS, int bs_, int tid) {
    int ldRow = tid >> 2;            // 0..63
    int ldCol = (tid & 3) * 8;       // element col within BK=32
    gload_lds16(As + (ldRow)      * 32 + ldCol, aS + (size_t)(ldRow)      * as_ + ldCol);
    gload_lds16(As + (ldRow + 64) * 32 + ldCol, aS + (size_t)(ldRow + 64) * as_ + ldCol);
    gload_lds16(Bs + (ldRow)      * 32 + ldCol, bS + (size_t)(ldRow)      * bs_ + ldCol);
    gload_lds16(Bs + (ldRow + 64) * 32 + ldCol, bS + (size_t)(ldRow + 64) * bs_ + ldCol);
}

__device__ __forceinline__ void compute_tile(const short* As, const short* Bs,
        int wr, int wc, int r, int ks, f32x4 (&acc)[4][4]) {
    bf16x8 a[4];
    #pragma unroll
    for (int m = 0; m < 4; ++m)
        a[m] = *(const bf16x8*)(As + (wr * 64 + m * 16 + r) * 32 + ks * 8);
    #pragma unroll
    for (int n = 0; n < 4; ++n) {
        bf16x8 b = *(const bf16x8*)(Bs + (wc * 64 + n * 16 + r) * 32 + ks * 8);
        #pragma unroll
        for (int m = 0; m < 4; ++m)
            acc[m][n] = __builtin_amdgcn_mfma_f32_16x16x32_bf16(a[m], b, acc[m][n], 0, 0, 0);
    }
}

// NK even. Schedule per K-half-step: STAGE(next) -> COMPUTE(cur) -> barrier.
template<int NK>
__device__ __forceinline__ void gemm_tile(
        const short* __restrict__ aBase, int as_,
        const short* __restrict__ bBase, int bs_,
        short* As0, short* Bs0, short* As1, short* Bs1, f32x4 (&acc)[4][4]) {
    int tid = threadIdx.x;
    int lane = tid & 63, wave = tid >> 6;
    int wr = wave >> 1, wc = wave & 1;
    int r = lane & 15, ks = lane >> 4;
    stage_tile(As0, Bs0, aBase, as_, bBase, bs_, tid);
    __syncthreads();
    #pragma unroll
    for (int kt = 0; kt < NK; kt += 2) {
        if (kt + 1 < NK)
            stage_tile(As1, Bs1, aBase + (kt + 1) * 32, as_, bBase + (kt + 1) * 32, bs_, tid);
        compute_tile(As0, Bs0, wr, wc, r, ks, acc);
        __syncthreads();
        if (kt + 2 < NK)
            stage_tile(As0, Bs0, aBase + (kt + 2) * 32, as_, bBase + (kt + 2) * 32, bs_, tid);
        compute_tile(As1, Bs1, wr, wc, r, ks, acc);
        __syncthreads();
    }
}

#define GEMM_LDS \
    __shared__ short As0[128 * 32], Bs0[128 * 32], As1[128 * 32], Bs1[128 * 32]

// ---------------- q' projection: q'[n][g*128+e] = sum_d x[n][g*128+d] * Mt[g][e][d] ---
__global__ __launch_bounds__(256) void qproj_kernel(
        const short* __restrict__ x, const short* __restrict__ mt,
        short* __restrict__ qp) {
    GEMM_LDS;
    int nwg = gridDim.x;             // 782*4 = 3128, %8==0
    int bid = blockIdx.x;
    int tile = (bid & 7) * (nwg >> 3) + (bid >> 3);
    int rb = tile >> 2, g = tile & 3;
    int rowbase = rb * 128;
    int tid = threadIdx.x;
    int lane = tid & 63, wave = tid >> 6;
    int wr = wave >> 1, wc = wave & 1;
    int r = lane & 15, ks = lane >> 4;
    f32x4 acc[4][4];
    #pragma unroll
    for (int m = 0; m < 4; ++m)
        #pragma unroll
        for (int n = 0; n < 4; ++n)
            #pragma unroll
            for (int e = 0; e < 4; ++e) acc[m][n][e] = 0.0f;
    gemm_tile<4>(x + (size_t)rowbase * DIM + g * GD, DIM,
                 mt + (size_t)g * GD * GD, GD, As0, Bs0, As1, Bs1, acc);
    #pragma unroll
    for (int m = 0; m < 4; ++m)
        #pragma unroll
        for (int n = 0; n < 4; ++n)
            #pragma unroll
            for (int rr = 0; rr < 4; ++rr) {
                int orow = rowbase + wr * 64 + m * 16 + ks * 4 + rr;
                int lcol = wc * 64 + n * 16 + r;
                qp[(size_t)orow * DIM + g * GD + lcol] = f2bf(acc[m][n][rr]);
            }
}

// ---------------- attention: gathers x only; t[n][g] = sum_j softmax_j * x_j[g-slice] -
__global__ __launch_bounds__(256) void attn_kernel(
        const short* __restrict__ qp, const short* __restrict__ x,
        const int* __restrict__ nbrs, short* __restrict__ t_out) {
    int b = blockIdx.x;
    int xcd = b & 7;
    int g = xcd >> 1;
    int quad = (b >> 3) * 2 + (xcd & 1);   // 0..24999
    int tid = threadIdx.x;
    int wv = tid >> 6, lane = tid & 63;
    int n = quad * 4 + wv;                 // 0..99999
    int s = lane >> 4, t = lane & 15;
    int4 nbj = *(const int4*)(nbrs + (size_t)n * K_NBR + s * 4);
    int nbarr[4] = {nbj.x, nbj.y, nbj.z, nbj.w};
    size_t goff = (size_t)g * GD + t * 8;
    size_t qbase = (size_t)n * DIM + goff;
    bf16x8 qf = *(const bf16x8*)(qp + qbase);
    float qv[8];
    #pragma unroll
    for (int e = 0; e < 8; ++e) qv[e] = bf2f(qf[e]);
    bf16x8 xf[4];
    #pragma unroll
    for (int p = 0; p < 4; ++p)
        xf[p] = *(const bf16x8*)(x + (size_t)nbarr[p] * DIM + goff);
    float sc[4];
    #pragma unroll
    for (int p = 0; p < 4; ++p) {
        float dd = 0.0f;
        #pragma unroll
        for (int e = 0; e < 8; ++e) dd += qv[e] * bf2f(xf[p][e]);
        dd += __shfl_xor(dd, 1);
        dd += __shfl_xor(dd, 2);
        dd += __shfl_xor(dd, 4);
        dd += __shfl_xor(dd, 8);
        sc[p] = dd;
    }
    float mx = fmaxf(fmaxf(sc[0], sc[1]), fmaxf(sc[2], sc[3]));
    mx = fmaxf(mx, __shfl_xor(mx, 16));
    mx = fmaxf(mx, __shfl_xor(mx, 32));
    float ew[4]; float ssum = 0.0f;
    #pragma unroll
    for (int p = 0; p < 4; ++p) { ew[p] = __expf(sc[p] - mx); ssum += ew[p]; }
    ssum += __shfl_xor(ssum, 16);
    ssum += __shfl_xor(ssum, 32);
    float acc[8];
    #pragma unroll
    for (int d0 = 0; d0 < 8; ++d0) acc[d0] = 0.0f;
    #pragma unroll
    for (int p = 0; p < 4; ++p) {
        #pragma unroll
        for (int d0 = 0; d0 < 8; ++d0) acc[d0] += ew[p] * bf2f(xf[p][d0]);
    }
    #pragma unroll
    for (int d0 = 0; d0 < 8; ++d0) {
        acc[d0] += __shfl_xor(acc[d0], 16);
        acc[d0] += __shfl_xor(acc[d0], 32);
    }
    if (s == 0) {
        float inv = 1.0f / ssum;
        bf16x8 o;
        #pragma unroll
        for (int d0 = 0; d0 < 8; ++d0) o[d0] = f2bf(acc[d0] * inv);
        *(bf16x8*)(t_out + qbase) = o;
    }
}

// ------- res2 = t @ Wov.T + bo + features (residual), stored BF16 (102MB not 205) ----
__global__ __launch_bounds__(256) void outproj_kernel(
        const short* __restrict__ tbuf, const short* __restrict__ wov,
        const float* __restrict__ bo, const float* __restrict__ features,
        short* __restrict__ res2) {
    GEMM_LDS;
    int nwg = gridDim.x;             // 782*4
    int bid = blockIdx.x;
    int tile = (bid & 7) * (nwg >> 3) + (bid >> 3);
    int rb = tile >> 2, cb = tile & 3;
    int rowbase = rb * 128, colbase = cb * 128;
    int tid = threadIdx.x;
    int lane = tid & 63, wave = tid >> 6;
    int wr = wave >> 1, wc = wave & 1;
    int r = lane & 15, ks = lane >> 4;
    f32x4 acc[4][4];
    #pragma unroll
    for (int m = 0; m < 4; ++m)
        #pragma unroll
        for (int n = 0; n < 4; ++n)
            #pragma unroll
            for (int e = 0; e < 4; ++e) acc[m][n][e] = 0.0f;
    gemm_tile<16>(tbuf + (size_t)rowbase * DIM, DIM,
                  wov + (size_t)colbase * DIM, DIM, As0, Bs0, As1, Bs1, acc);
    #pragma unroll
    for (int m = 0; m < 4; ++m)
        #pragma unroll
        for (int n = 0; n < 4; ++n)
            #pragma unroll
            for (int rr = 0; rr < 4; ++rr) {
                int orow = rowbase + wr * 64 + m * 16 + ks * 4 + rr;
                int ocol = colbase + wc * 64 + n * 16 + r;
                if (orow < NPTS) {
                    float val = acc[m][n][rr] + bo[ocol] + features[(size_t)orow * DIM + ocol];
                    res2[(size_t)orow * DIM + ocol] = f2bf(val);
                }
            }
}

// ---------------- FFN1: h = gelu(y @ W1.T + b1), bf16 out, N=1024 --------------------
__global__ __launch_bounds__(256) void ffn1_kernel(
        const short* __restrict__ y, const short* __restrict__ w1,
        const float* __restrict__ b1, short* __restrict__ h) {
    GEMM_LDS;
    int nwg = gridDim.x;             // 782*8
    int bid = blockIdx.x;
    int tile = (bid & 7) * (nwg >> 3) + (bid >> 3);
    int rb = tile >> 3, cb = tile & 7;
    int rowbase = rb * 128, colbase = cb * 128;
    int tid = threadIdx.x;
    int lane = tid & 63, wave = tid >> 6;
    int wr = wave >> 1, wc = wave & 1;
    int r = lane & 15, ks = lane >> 4;
    f32x4 acc[4][4];
    #pragma unroll
    for (int m = 0; m < 4; ++m)
        #pragma unroll
        for (int n = 0; n < 4; ++n)
            #pragma unroll
            for (int e = 0; e < 4; ++e) acc[m][n][e] = 0.0f;
    gemm_tile<16>(y + (size_t)rowbase * DIM, DIM,
                  w1 + (size_t)colbase * DIM, DIM, As0, Bs0, As1, Bs1, acc);
    #pragma unroll
    for (int m = 0; m < 4; ++m)
        #pragma unroll
        for (int n = 0; n < 4; ++n)
            #pragma unroll
            for (int rr = 0; rr < 4; ++rr) {
                int orow = rowbase + wr * 64 + m * 16 + ks * 4 + rr;
                int ocol = colbase + wc * 64 + n * 16 + r;
                float xv = acc[m][n][rr] + b1[ocol];
                // exact-GELU via clamped tanh form (max abs err ~3e-3)
                float xc = fminf(fmaxf(xv, -9.0f), 9.0f);
                float u = xc * (0.7978845608028654f + 0.0356774081f * xc * xc);
                float e2 = __expf(2.0f * u);
                float th = (e2 - 1.0f) / (e2 + 1.0f);
                float gl = 0.5f * xv * (1.0f + th);
                h[(size_t)orow * (2 * DIM) + ocol] = f2bf(gl);
            }
}

// ------- FFN2: d_out = h @ W2.T + b2 + res2(bf16), plain f32 store (no d_out read) ---
__global__ __launch_bounds__(256) void ffn2_kernel(
        const short* __restrict__ h, const short* __restrict__ w2,
        const float* __restrict__ b2, const short* __restrict__ res2,
        float* __restrict__ out) {
    GEMM_LDS;
    int nwg = gridDim.x;             // 782*4
    int bid = blockIdx.x;
    int tile = (bid & 7) * (nwg >> 3) + (bid >> 3);
    int rb = tile >> 2, cb = tile & 3;
    int rowbase = rb * 128, colbase = cb * 128;
    int tid = threadIdx.x;
    int lane = tid & 63, wave = tid >> 6;
    int wr = wave >> 1, wc = wave & 1;
    int r = lane & 15, ks = lane >> 4;
    f32x4 acc[4][4];
    #pragma unroll
    for (int m = 0; m < 4; ++m)
        #pragma unroll
        for (int n = 0; n < 4; ++n)
            #pragma unroll
            for (int e = 0; e < 4; ++e) acc[m][n][e] = 0.0f;
    gemm_tile<32>(h + (size_t)rowbase * (2 * DIM), 2 * DIM,
                  w2 + (size_t)colbase * (2 * DIM), 2 * DIM, As0, Bs0, As1, Bs1, acc);
    #pragma unroll
    for (int m = 0; m < 4; ++m)
        #pragma unroll
        for (int n = 0; n < 4; ++n)
            #pragma unroll
            for (int rr = 0; rr < 4; ++rr) {
                int orow = rowbase + wr * 64 + m * 16 + ks * 4 + rr;
                int ocol = colbase + wc * 64 + n * 16 + r;
                if (orow < NPTS) {
                    size_t idx = (size_t)orow * DIM + ocol;
                    out[idx] = acc[m][n][rr] + b2[ocol] + bf2f(res2[idx]);
                }
            }
}

extern "C" void kernel_launch(void* const* d_in, const int* in_sizes, int n_in,
                              void* d_out, int out_size, void* d_ws, size_t ws_size,
                              hipStream_t stream) {
    const float* features = (const float*)d_in[0];
    const int*   neighbors = (const int*)d_in[2];
    const float* Wq = (const float*)d_in[3];
    const float* Wk = (const float*)d_in[4];
    const float* Wv = (const float*)d_in[5];
    const float* Wo = (const float*)d_in[6];
    const float* bo = (const float*)d_in[7];
    const float* ln1_g = (const float*)d_in[8];
    const float* ln1_b = (const float*)d_in[9];
    const float* ln2_g = (const float*)d_in[10];
    const float* ln2_b = (const float*)d_in[11];
    const float* W1 = (const float*)d_in[12];
    const float* b1 = (const float*)d_in[13];
    const float* W2 = (const float*)d_in[14];
    const float* b2 = (const float*)d_in[15];
    float* out = (float*)d_out;

    size_t slotElems = (size_t)PAD_ROWS * DIM;
    short* s0 = (short*)d_ws;            // x (ln1) -> y (ln2)
    short* s1 = s0 + slotElems;          // q' -> h (low half; s1+s2 contiguous = h[PAD][1024])
    short* s2 = s1 + slotElems;          // t  -> h (high half)
    short* s3 = s2 + slotElems;          // res2 (bf16)
    short* mt_b  = s3 + slotElems;       // 4*128*128
    short* wov_b = mt_b + GRP * GD * GD; // 512*512
    short* w1_b  = wov_b + DIM * DIM;    // 1024*512
    short* w2_b  = w1_b + 2 * DIM * DIM; // 512*1024

    cvt_kernel<<<256, 256, 0, stream>>>(W1, w1_b, 2 * DIM * DIM);
    cvt_kernel<<<256, 256, 0, stream>>>(W2, w2_b, 2 * DIM * DIM);
    prep_m_kernel<<<GRP * GD, GD, 0, stream>>>(Wq, Wk, mt_b);
    prep_wov_kernel<<<DIM, DIM, 0, stream>>>(Wo, Wv, wov_b);

    // LN1: features -> x (bf16), zero-padded rows
    ln_kernel<<<PAD_ROWS, 128, 0, stream>>>(features, ln1_g, ln1_b, s0);

    // q' = Mt x (single grouped GEMM pass)
    qproj_kernel<<<(PAD_ROWS / 128) * 4, 256, 0, stream>>>(s0, mt_b, s1);

    // attention: gather x only -> t in s2
    attn_kernel<<<NPTS, 256, 0, stream>>>(s1, s0, neighbors, s2);

    // res2 = t @ Wov.T + bo + features  (bf16, in s3)
    outproj_kernel<<<(PAD_ROWS / 128) * 4, 256, 0, stream>>>(s2, wov_b, bo, features, s3);

    // LN2: res2 (bf16) -> y (bf16) in s0
    ln_bf16_kernel<<<PAD_ROWS, 128, 0, stream>>>(s3, ln2_g, ln2_b, s0);

    // FFN1: h = gelu(y @ W1.T + b1) -> s1..s2 region (PAD x 1024 bf16)
    ffn1_kernel<<<(PAD_ROWS / 128) * 8, 256, 0, stream>>>(s0, w1_b, b1, s1);

    // FFN2: d_out = h @ W2.T + b2 + res2
    ffn2_kernel<<<(PAD_ROWS / 128) * 4, 256, 0, stream>>>(s1, w2_b, b2, s3, out);
}